// Round 3
// baseline (2747.421 us; speedup 1.0000x reference)
//
#include <hip/hip_runtime.h>
#include <hip/hip_fp16.h>

#define HID 16
#define NFEAT 512

// fire-and-forget packed fp16 atomic add (2 features per op)
__device__ __forceinline__ void pk_atomic_add_f16(unsigned int* addr, unsigned int data) {
    asm volatile("global_atomic_pk_add_f16 %0, %1, off" :: "v"(addr), "v"(data) : "memory");
}

// ---------------------------------------------------------------- degree
__global__ __launch_bounds__(256) void deg_count_int(const int* __restrict__ dst,
                                                     int* __restrict__ ideg, int e) {
    int i = blockIdx.x * 256 + threadIdx.x;
    if (i < e) atomicAdd(&ideg[dst[i]], 1);
}

__global__ __launch_bounds__(256) void make_dis(const int* __restrict__ ideg,
                                                float* __restrict__ dis, int n) {
    int i = blockIdx.x * 256 + threadIdx.x;
    if (i < n) dis[i] = rsqrtf(1.0f + (float)ideg[i]);
}

// ---------------------------------------------------------------- h1 = x @ W1
// Block = 256 thr = 16 rows x 16 k-chunks. W1 staged TRANSPOSED in LDS; x reads
// coalesced (4 x 256B segments per wave instruction); 16-way partial reduction
// via padded LDS.
__global__ __launch_bounds__(256) void mm1(const float* __restrict__ x,
                                           const float* __restrict__ W1,
                                           float* __restrict__ h1, int n) {
    __shared__ float lds[NFEAT * HID];        // 32 KB: W1t, then reused as red[]
    float* W1t = lds;                         // [16][512]
    for (int idx = threadIdx.x; idx < NFEAT * HID / 4; idx += 256) {
        int k = idx >> 2, j0 = (idx & 3) * 4;
        float4 v = ((const float4*)W1)[idx];
        W1t[(j0 + 0) * NFEAT + k] = v.x;
        W1t[(j0 + 1) * NFEAT + k] = v.y;
        W1t[(j0 + 2) * NFEAT + k] = v.z;
        W1t[(j0 + 3) * NFEAT + k] = v.w;
    }
    __syncthreads();

    int r = threadIdx.x >> 4;                 // row within block
    int c = threadIdx.x & 15;                 // k-chunk
    int row = blockIdx.x * 16 + r;
    bool active = (row < n);

    float acc[HID];
#pragma unroll
    for (int j = 0; j < HID; ++j) acc[j] = 0.f;

    if (active) {
        const float4* xr = (const float4*)x + (size_t)row * (NFEAT / 4);
#pragma unroll
        for (int i = 0; i < 8; ++i) {
            float4 xv = xr[i * 16 + c];
            int kb = i * 64 + c * 4;
#pragma unroll
            for (int j = 0; j < HID; ++j) {
                float4 w = *(const float4*)&W1t[j * NFEAT + kb];
                acc[j] += xv.x * w.x + xv.y * w.y + xv.z * w.z + xv.w * w.w;
            }
        }
    }
    __syncthreads();   // done with W1t; reuse lds as red[16][16][17]

    float* red = lds;
#pragma unroll
    for (int j = 0; j < HID; ++j)
        red[r * 272 + c * 17 + j] = acc[j];
    __syncthreads();

    float sum = 0.f;
#pragma unroll
    for (int cc = 0; cc < 16; ++cc)
        sum += red[r * 272 + cc * 17 + c];
    if (active)
        h1[(size_t)blockIdx.x * 256 + threadIdx.x] = sum;
}

// ---------------------------------------------------------------- propagation
// One thread per edge: read 64B h-row of src, scale, 8 packed-fp16 atomics to
// dst row. aggh is [n][8] uints (= [n][16] fp16).
__global__ __launch_bounds__(256) void prop_pk(const int* __restrict__ src,
                                               const int* __restrict__ dst,
                                               const float* __restrict__ dis,
                                               const float* __restrict__ h,
                                               unsigned int* __restrict__ aggh, int e) {
    int i = blockIdx.x * 256 + threadIdx.x;
    if (i >= e) return;
    int s = src[i], d = dst[i];
    float w = dis[s] * dis[d];
    const float4* hr = (const float4*)(h + (size_t)s * HID);
    unsigned int* ar = aggh + (size_t)d * 8;
#pragma unroll
    for (int q = 0; q < 4; ++q) {
        float4 hv = hr[q];
        __half2 p0 = __floats2half2_rn(hv.x * w, hv.y * w);
        __half2 p1 = __floats2half2_rn(hv.z * w, hv.w * w);
        pk_atomic_add_f16(ar + q * 2 + 0, *(unsigned int*)&p0);
        pk_atomic_add_f16(ar + q * 2 + 1, *(unsigned int*)&p1);
    }
}

// ---------------------------------------------------------------- fused middle
// h = relu(agg1 + h1*dis^2 + b1);  h2 = h @ W2; h2 overwrites h1.
// 8 threads per node, 2 features each.
__global__ __launch_bounds__(256) void mid(const unsigned int* __restrict__ agg1h,
                                           float* __restrict__ h1,
                                           const float* __restrict__ dis,
                                           const float* __restrict__ b1,
                                           const float* __restrict__ W2, int n) {
    __shared__ float W2s[HID * HID];
    W2s[threadIdx.x] = W2[threadIdx.x];
    __syncthreads();

    int idx = blockIdx.x * 256 + threadIdx.x;
    int v = idx >> 3, jp = idx & 7;
    if (v >= n) return;
    float dn = dis[v], dn2 = dn * dn;
    __half2 ah = *(const __half2*)&agg1h[idx];
    float2 ag = __half22float2(ah);
    float2 hs = *(const float2*)&h1[(size_t)v * HID + jp * 2];
    float ha = fmaxf(ag.x + hs.x * dn2 + b1[2 * jp + 0], 0.f);
    float hb = fmaxf(ag.y + hs.y * dn2 + b1[2 * jp + 1], 0.f);

    float a0 = 0.f, a1 = 0.f;
#pragma unroll
    for (int k = 0; k < 8; ++k) {
        float f0 = __shfl(ha, k, 8);   // feat 2k
        float f1 = __shfl(hb, k, 8);   // feat 2k+1
        a0 += f0 * W2s[(2 * k) * HID + 2 * jp]     + f1 * W2s[(2 * k + 1) * HID + 2 * jp];
        a1 += f0 * W2s[(2 * k) * HID + 2 * jp + 1] + f1 * W2s[(2 * k + 1) * HID + 2 * jp + 1];
    }
    *(float2*)&h1[(size_t)v * HID + jp * 2] = make_float2(a0, a1);
}

// z = agg2 + h2*dis^2 + b2;  out = z + eps*exp(0.5*z)
__global__ __launch_bounds__(256) void finalk(float* __restrict__ out,
                                              const unsigned int* __restrict__ agg2h,
                                              const float* __restrict__ h2,
                                              const float* __restrict__ dis,
                                              const float* __restrict__ b2,
                                              const float* __restrict__ eps, int n) {
    int idx = blockIdx.x * 256 + threadIdx.x;
    int v = idx >> 3, jp = idx & 7;
    if (v >= n) return;
    float dn = dis[v], dn2 = dn * dn;
    float2 ag = __half22float2(*(const __half2*)&agg2h[idx]);
    float2 hv = *(const float2*)&h2[(size_t)v * HID + jp * 2];
    float2 ep = *(const float2*)&eps[(size_t)v * HID + jp * 2];
    float z0 = ag.x + hv.x * dn2 + b2[2 * jp + 0];
    float z1 = ag.y + hv.y * dn2 + b2[2 * jp + 1];
    float o0 = z0 + ep.x * expf(0.5f * z0);
    float o1 = z1 + ep.y * expf(0.5f * z1);
    *(float2*)&out[(size_t)v * HID + jp * 2] = make_float2(o0, o1);
}

extern "C" void kernel_launch(void* const* d_in, const int* in_sizes, int n_in,
                              void* d_out, int out_size, void* d_ws, size_t ws_size,
                              hipStream_t stream) {
    const float* x   = (const float*)d_in[0];
    const float* W1  = (const float*)d_in[1];
    const float* b1  = (const float*)d_in[2];
    const float* W2  = (const float*)d_in[3];
    const float* b2  = (const float*)d_in[4];
    const float* eps = (const float*)d_in[5];
    const int*   ei  = (const int*)d_in[6];

    int n = in_sizes[5] / HID;   // 100000
    int e = in_sizes[6] / 2;     // 3200000
    const int* srcs = ei;
    const int* dsts = ei + e;

    // ws layout: [ideg n][agg1h n*8][agg2h n*8] (zeroed together) [dis n][h1 n*16]
    int*          ideg  = (int*)d_ws;
    unsigned int* agg1h = (unsigned int*)(ideg + n);
    unsigned int* agg2h = agg1h + (size_t)n * 8;
    float*        dis   = (float*)(agg2h + (size_t)n * 8);
    float*        h1    = dis + n;
    float*        outf  = (float*)d_out;

    hipMemsetAsync(ideg, 0, (size_t)n * 68, stream);   // ideg + both agg buffers

    int nBlk   = (n + 255) / 256;
    int eBlk   = (e + 255) / 256;
    int rowBlk = (n + 15) / 16;
    int pBlk   = (n * 8 + 255) / 256;

    deg_count_int<<<eBlk, 256, 0, stream>>>(dsts, ideg, e);
    make_dis<<<nBlk, 256, 0, stream>>>(ideg, dis, n);

    mm1<<<rowBlk, 256, 0, stream>>>(x, W1, h1, n);

    prop_pk<<<eBlk, 256, 0, stream>>>(srcs, dsts, dis, h1, agg1h, e);
    mid<<<pBlk, 256, 0, stream>>>(agg1h, h1, dis, b1, W2, n);
    prop_pk<<<eBlk, 256, 0, stream>>>(srcs, dsts, dis, h1, agg2h, e);
    finalk<<<pBlk, 256, 0, stream>>>(outf, agg2h, h1, dis, b2, eps, n);
}

// Round 4
// 687.653 us; speedup vs baseline: 3.9954x; 3.9954x over previous
//
#include <hip/hip_runtime.h>

#define HID 16
#define NFEAT 512

// ---------------------------------------------------------------- degree
__global__ __launch_bounds__(256) void deg_count_int(const int* __restrict__ dst,
                                                     int* __restrict__ ideg, int e) {
    int i = blockIdx.x * 256 + threadIdx.x;
    if (i < e) atomicAdd(&ideg[dst[i]], 1);
}

__global__ __launch_bounds__(256) void make_dis(const int* __restrict__ ideg,
                                                float* __restrict__ dis, int n) {
    int i = blockIdx.x * 256 + threadIdx.x;
    if (i < n) dis[i] = rsqrtf(1.0f + (float)ideg[i]);
}

// ---------------------------------------------------------------- h1 = x @ W1
// Block = 256 threads = 16 (k-chunk groups of 4 rows) x 16 k-chunks.
// Each thread processes 4 rows for its k-slice: one ds_read_b128 of W feeds
// 4 rows' FMAs (LDS traffic /4 vs 1-row version). x loads coalesced
// (4 x 256B segments per wave instr). 4-pass padded-LDS reduction.
__global__ __launch_bounds__(256) void mm1(const float* __restrict__ x,
                                           const float* __restrict__ W1,
                                           float* __restrict__ h1, int n) {
    __shared__ float lds[NFEAT * HID];        // 32 KB: W1t, then reused as red[]
    float* W1t = lds;                         // [16][512]
    for (int idx = threadIdx.x; idx < NFEAT * HID / 4; idx += 256) {
        int k = idx >> 2, j0 = (idx & 3) * 4;
        float4 v = ((const float4*)W1)[idx];
        W1t[(j0 + 0) * NFEAT + k] = v.x;
        W1t[(j0 + 1) * NFEAT + k] = v.y;
        W1t[(j0 + 2) * NFEAT + k] = v.z;
        W1t[(j0 + 3) * NFEAT + k] = v.w;
    }
    __syncthreads();

    int r4 = threadIdx.x >> 4;                // 0..15: row-group
    int c  = threadIdx.x & 15;                // k-chunk
    int row0 = blockIdx.x * 64 + r4 * 4;

    float acc[4][HID];
#pragma unroll
    for (int q = 0; q < 4; ++q)
#pragma unroll
        for (int j = 0; j < HID; ++j) acc[q][j] = 0.f;

    const float4* xb = (const float4*)x;
    bool full = (row0 + 3 < n);

#pragma unroll
    for (int i = 0; i < 8; ++i) {
        float4 xv[4];
        if (full) {
#pragma unroll
            for (int q = 0; q < 4; ++q)
                xv[q] = xb[(size_t)(row0 + q) * (NFEAT / 4) + i * 16 + c];
        } else {
#pragma unroll
            for (int q = 0; q < 4; ++q)
                xv[q] = (row0 + q < n)
                          ? xb[(size_t)(row0 + q) * (NFEAT / 4) + i * 16 + c]
                          : make_float4(0.f, 0.f, 0.f, 0.f);
        }
#pragma unroll
        for (int j = 0; j < HID; ++j) {
            float4 w = *(const float4*)&W1t[j * NFEAT + i * 64 + c * 4];
#pragma unroll
            for (int q = 0; q < 4; ++q)
                acc[q][j] += xv[q].x * w.x + xv[q].y * w.y + xv[q].z * w.z + xv[q].w * w.w;
        }
    }
    __syncthreads();   // done with W1t; reuse lds as red[16][16][17]

    float* red = lds;
#pragma unroll 1
    for (int q = 0; q < 4; ++q) {
#pragma unroll
        for (int j = 0; j < HID; ++j)
            red[r4 * 272 + c * 17 + j] = acc[q][j];
        __syncthreads();
        float sum = 0.f;
#pragma unroll
        for (int cc = 0; cc < 16; ++cc)
            sum += red[r4 * 272 + cc * 17 + c];
        int row = row0 + q;
        if (row < n) h1[(size_t)row * HID + c] = sum;
        __syncthreads();
    }
}

// ---------------------------------------------------------------- propagation
// agg[dst] += h[src] * dis[src]*dis[dst] — one thread per (edge, feature),
// fp32 atomics (execute at memory-side cache, no HBM RMW).
__global__ __launch_bounds__(256) void prop_atomic(const int* __restrict__ src,
                                                   const int* __restrict__ dst,
                                                   const float* __restrict__ dis,
                                                   const float* __restrict__ h,
                                                   float* __restrict__ agg, int e) {
    int idx = blockIdx.x * 256 + threadIdx.x;   // e*16 = 51.2M < 2^31
    int ed = idx >> 4, j = idx & 15;
    if (ed >= e) return;
    int s = src[ed], d = dst[ed];
    float w = dis[s] * dis[d];
    atomicAdd(&agg[(size_t)d * HID + j], h[(size_t)s * HID + j] * w);
}

// ---------------------------------------------------------------- fused middle
// h = relu(agg1 + h1*dis^2 + b1);  h2 = h @ W2 (intra-16-lane shuffles); h2 -> h1
__global__ __launch_bounds__(256) void mid(const float* __restrict__ agg1,
                                           float* __restrict__ h1,
                                           const float* __restrict__ dis,
                                           const float* __restrict__ b1,
                                           const float* __restrict__ W2, int n) {
    __shared__ float W2s[HID * HID];
    if (threadIdx.x < HID * HID) W2s[threadIdx.x] = W2[threadIdx.x];
    __syncthreads();

    int idx = blockIdx.x * 256 + threadIdx.x;
    int nrow = idx >> 4, j = idx & 15;
    if (nrow >= n) return;
    float dn = dis[nrow];
    float a = agg1[idx] + h1[idx] * dn * dn + b1[j];
    float hv = fmaxf(a, 0.f);
    float h2 = 0.f;
#pragma unroll
    for (int k = 0; k < HID; ++k)
        h2 += __shfl(hv, k, HID) * W2s[k * HID + j];
    h1[idx] = h2;
}

// z = agg2 + h2*dis^2 + b2;  out = z + eps*exp(0.5*z)   (agg2 accumulated in d_out)
__global__ __launch_bounds__(256) void finalk(float* __restrict__ out,
                                              const float* __restrict__ h2,
                                              const float* __restrict__ dis,
                                              const float* __restrict__ b2,
                                              const float* __restrict__ eps, int n) {
    int idx = blockIdx.x * 256 + threadIdx.x;
    int nrow = idx >> 4, j = idx & 15;
    if (nrow >= n) return;
    float dn = dis[nrow];
    float z = out[idx] + h2[idx] * dn * dn + b2[j];
    out[idx] = z + eps[idx] * expf(0.5f * z);
}

extern "C" void kernel_launch(void* const* d_in, const int* in_sizes, int n_in,
                              void* d_out, int out_size, void* d_ws, size_t ws_size,
                              hipStream_t stream) {
    const float* x   = (const float*)d_in[0];
    const float* W1  = (const float*)d_in[1];
    const float* b1  = (const float*)d_in[2];
    const float* W2  = (const float*)d_in[3];
    const float* b2  = (const float*)d_in[4];
    const float* eps = (const float*)d_in[5];
    const int*   ei  = (const int*)d_in[6];

    int n = in_sizes[5] / HID;   // 100000
    int e = in_sizes[6] / 2;     // 3200000
    const int* srcs = ei;
    const int* dsts = ei + e;

    // ws layout: [ideg n][dis n][h1 n*16][agg1 n*16]
    int*   ideg = (int*)d_ws;
    float* dis  = (float*)(ideg + n);
    float* h1   = dis + n;
    float* agg1 = h1 + (size_t)n * HID;
    float* outf = (float*)d_out;

    size_t featBytes = (size_t)n * HID * sizeof(float);
    hipMemsetAsync(ideg, 0, (size_t)n * sizeof(int), stream);
    hipMemsetAsync(agg1, 0, featBytes, stream);
    hipMemsetAsync(outf, 0, featBytes, stream);

    int nBlk   = (n + 255) / 256;
    int eBlk   = (e + 255) / 256;
    int mmBlk  = (n + 63) / 64;
    int featBlk = (n * 16 + 255) / 256;
    int propBlk = (e * 16 + 255) / 256;

    deg_count_int<<<eBlk, 256, 0, stream>>>(dsts, ideg, e);
    make_dis<<<nBlk, 256, 0, stream>>>(ideg, dis, n);

    mm1<<<mmBlk, 256, 0, stream>>>(x, W1, h1, n);

    prop_atomic<<<propBlk, 256, 0, stream>>>(srcs, dsts, dis, h1, agg1, e);
    mid<<<featBlk, 256, 0, stream>>>(agg1, h1, dis, b1, W2, n);
    prop_atomic<<<propBlk, 256, 0, stream>>>(srcs, dsts, dis, h1, outf, e);
    finalk<<<featBlk, 256, 0, stream>>>(outf, h1, dis, b2, eps, n);
}